// Round 4
// baseline (253.232 us; speedup 1.0000x reference)
//
#include <hip/hip_runtime.h>
#include <hip/hip_bf16.h>

// GATConv, N=8192, F_in=F_out=128, dense 0/1 adjacency (int32).
// Rank-1 logits: e_ij = LeakyReLU(es_i + ed_j), es = X@(W@a_src), ed = X@(W@a_dst).
// No max-shift needed (|logit| <~ 9 -> exp safe in f32); partial sums are additive.
//
// R3 structure (resubmitted after infra failure): the 256 MB A-stream is
// decoupled into a trivial pack kernel (A -> 8 MB bitmask, diagonal OR'd in).
// The main kernel then has NO HBM latency to hide (masks L3-hot, HbT/ed
// L2-hot) -> short VALU/MFMA kernel.

typedef __bf16 bf16_t;
typedef bf16_t bf16x8 __attribute__((ext_vector_type(8)));
typedef float  f32x4  __attribute__((ext_vector_type(4)));
typedef int    i32x4  __attribute__((ext_vector_type(4)));

#define NN 8192
#define DD 128
#define NW 256  // mask words per row (8192/32)

// ---- kA: pack adjacency to bitmask, self-loop diagonal OR'd in ----
// One thread per output u32 word: reads 32 ints (128 B), writes 4 B.
__global__ __launch_bounds__(256) void kA_pack(const int* __restrict__ A,
                                               unsigned* __restrict__ bits) {
  const int w = blockIdx.x * 256 + threadIdx.x;  // word id, 0..2M-1
  const i32x4* p = (const i32x4*)(A + (size_t)w * 32);
  i32x4 v[8];
  #pragma unroll
  for (int q = 0; q < 8; ++q) v[q] = __builtin_nontemporal_load(p + q);
  unsigned m = 0;
  #pragma unroll
  for (int q = 0; q < 8; ++q) {
    #pragma unroll
    for (int e = 0; e < 4; ++e) m |= ((unsigned)v[q][e]) << (q * 4 + e);  // A is 0/1
  }
  const int row = w >> 8;           // w / NW
  const int c0 = (w & 255) << 5;    // first col of this word
  if (row >= c0 && row < c0 + 32) m |= 1u << (row - c0);  // self-loop
  bits[w] = m;
}

// ---- K1: fused wv = W@a_{src,dst}; es/ed = X@wv; HbT = bf16(X@W)^T ----
__global__ __launch_bounds__(256) void k1_fused(const float* __restrict__ X,
                                                const float* __restrict__ W,
                                                const float* __restrict__ a_src,
                                                const float* __restrict__ a_dst,
                                                float* __restrict__ es,
                                                float* __restrict__ ed,
                                                bf16_t* __restrict__ HbT) {
  __shared__ float Wl[DD * DD];    // 64 KB; [0..256) aliased wsv/wdv, [256..320) es/ed scratch
  __shared__ bf16_t Tl[DD][40];    // transposed H tile [c][r], 80 B rows (16B-aligned)
  const int t = threadIdx.x;
  const int rb = blockIdx.x << 5;  // 32 rows per block

  // Phase 1: wsv (t<128) / wdv (t>=128)
  {
    const int k = t & 127;
    const float* av = (t < 128) ? a_src : a_dst;
    const f32x4* wrow = (const f32x4*)(W + k * DD);
    float s = 0.f;
    #pragma unroll
    for (int c4 = 0; c4 < 32; ++c4) {
      const f32x4 wv = wrow[c4];
      const f32x4 avv = *(const f32x4*)(av + c4 * 4);
      s += wv[0] * avv[0] + wv[1] * avv[1] + wv[2] * avv[2] + wv[3] * avv[3];
    }
    Wl[t] = s;
  }
  if (t < 64) Wl[256 + t] = 0.f;
  __syncthreads();

  // Phase 2: es/ed for this block's 32 rows
  {
    const int r = t >> 3, part = t & 7;
    const f32x4* xrow = (const f32x4*)(X + (size_t)(rb + r) * DD + part * 16);
    float s = 0.f, d = 0.f;
    #pragma unroll
    for (int q = 0; q < 4; ++q) {
      const f32x4 xv = xrow[q];
      const f32x4 sv = *(const f32x4*)(Wl + part * 16 + q * 4);
      const f32x4 dv = *(const f32x4*)(Wl + 128 + part * 16 + q * 4);
      s += xv[0] * sv[0] + xv[1] * sv[1] + xv[2] * sv[2] + xv[3] * sv[3];
      d += xv[0] * dv[0] + xv[1] * dv[1] + xv[2] * dv[2] + xv[3] * dv[3];
    }
    atomicAdd(&Wl[256 + r], s);
    atomicAdd(&Wl[288 + r], d);
  }
  __syncthreads();
  if (t < 32) es[rb + t] = Wl[256 + t];
  else if (t < 64) ed[rb + t - 32] = Wl[288 + t - 32];
  __syncthreads();

  // Phase 3: stage full W in LDS
  for (int idx = t; idx < DD * DD; idx += 256) Wl[idx] = W[idx];
  __syncthreads();

  // Phase 4: H tile -> LDS transposed
  const int c = t & 127;
  const int r0 = t >> 7;
  for (int rr = 0; rr < 16; ++rr) {
    const int r = (rr << 1) + r0;
    const f32x4* xrow = (const f32x4*)(X + (size_t)(rb + r) * DD);
    float acc = 0.f;
    #pragma unroll
    for (int k4 = 0; k4 < 32; ++k4) {
      const f32x4 xv = xrow[k4];
      acc += xv[0] * Wl[(k4 * 4 + 0) * DD + c] + xv[1] * Wl[(k4 * 4 + 1) * DD + c] +
             xv[2] * Wl[(k4 * 4 + 2) * DD + c] + xv[3] * Wl[(k4 * 4 + 3) * DD + c];
    }
    Tl[c][r] = (bf16_t)acc;
  }
  __syncthreads();

  // write-out: thread t -> column c2 = t>>1, half = t&1 (16 rows = 32 B contiguous)
  {
    const int c2 = t >> 1, half = t & 1;
    const bf16x8 u0 = *(const bf16x8*)&Tl[c2][half * 16];
    const bf16x8 u1 = *(const bf16x8*)&Tl[c2][half * 16 + 8];
    bf16_t* dst = HbT + (size_t)c2 * NN + rb + half * 16;
    *(bf16x8*)dst = u0;
    *(bf16x8*)(dst + 8) = u1;
  }
}

// ---- K2: main. 256 WGs x 512 thr; WG owns 32 rows, lane owns rows i0,i0+16. ----
// Wave w handles contiguous j in [w*1024, (w+1)*1024), 32 steps of 32 j.
// Per step: 2 mask u32 (register, prefetched 4-steps-deep), 8x f32 ed (L1),
// 8x 16B V frags (L2), 16 exps, 16 MFMA.
__global__ __launch_bounds__(512) void k2_gat(const unsigned* __restrict__ bits,
                                              const float* __restrict__ es,
                                              const float* __restrict__ ed,
                                              const bf16_t* __restrict__ HbT,
                                              float* __restrict__ out) {
  __shared__ float numLDS[32 * DD];  // 16 KB
  __shared__ float denLDS[32];
  const int t = threadIdx.x;
  for (int idx = t; idx < 32 * DD; idx += 512) numLDS[idx] = 0.f;
  if (t < 32) denLDS[t] = 0.f;
  __syncthreads();

  const int wave = t >> 6;
  const int lane = t & 63;
  const int l16 = lane & 15;
  const int lk = lane >> 4;  // 0..3
  const int rowbase = blockIdx.x << 5;
  const int i0 = rowbase + l16;
  const int i1 = i0 + 16;
  const float esv0 = es[i0];
  const float esv1 = es[i1];
  const unsigned* M0 = bits + (size_t)i0 * NW;
  const unsigned* M1 = bits + (size_t)i1 * NW;
  const int wj = wave << 10;  // wave's j base

  f32x4 acc0[8], acc1[8];
  #pragma unroll
  for (int cf = 0; cf < 8; ++cf) {
    acc0[cf] = f32x4{0.f, 0.f, 0.f, 0.f};
    acc1[cf] = f32x4{0.f, 0.f, 0.f, 0.f};
  }
  float den0 = 0.f, den1 = 0.f;

  i32x4 m0 = *(const i32x4*)(M0 + (wave << 5));
  i32x4 m1 = *(const i32x4*)(M1 + (wave << 5));

  for (int g = 0; g < 8; ++g) {
    i32x4 n0 = m0, n1 = m1;
    if (g < 7) {  // prefetch next 4-step group's masks
      n0 = *(const i32x4*)(M0 + (wave << 5) + (g + 1) * 4);
      n1 = *(const i32x4*)(M1 + (wave << 5) + (g + 1) * 4);
    }
    #pragma unroll
    for (int ds = 0; ds < 4; ++ds) {
      const int jj = wj + ((g << 2) + ds) * 32 + (lk << 3);
      const f32x4 y0 = *(const f32x4*)(ed + jj);
      const f32x4 y1 = *(const f32x4*)(ed + jj + 4);
      const unsigned w0 = ((unsigned)m0[ds]) >> (lk << 3);
      const unsigned w1 = ((unsigned)m1[ds]) >> (lk << 3);
      bf16x8 pa0, pa1;
      float ps0 = 0.f, ps1 = 0.f;
      #pragma unroll
      for (int q = 0; q < 8; ++q) {
        const float edq = (q < 4) ? y0[q] : y1[q - 4];
        float e0 = esv0 + edq;
        e0 = fmaxf(e0, 0.2f * e0);  // LeakyReLU(0.2)
        float e1 = esv1 + edq;
        e1 = fmaxf(e1, 0.2f * e1);
        const float p0 = ((w0 >> q) & 1u) ? __expf(e0) : 0.f;
        const float p1 = ((w1 >> q) & 1u) ? __expf(e1) : 0.f;
        ps0 += p0;
        ps1 += p1;
        pa0[q] = (bf16_t)p0;
        pa1[q] = (bf16_t)p1;
      }
      den0 += ps0;
      den1 += ps1;
      const bf16_t* vbase = HbT + jj;
      #pragma unroll
      for (int cf = 0; cf < 8; ++cf) {
        const bf16x8 vb = *(const bf16x8*)(vbase + (size_t)(cf * 16 + l16) * NN);
        acc0[cf] = __builtin_amdgcn_mfma_f32_16x16x32_bf16(pa0, vb, acc0[cf], 0, 0, 0);
        acc1[cf] = __builtin_amdgcn_mfma_f32_16x16x32_bf16(pa1, vb, acc1[cf], 0, 0, 0);
      }
    }
    m0 = n0;
    m1 = n1;
  }

  // cross-wave reduction (order-independent additive sums)
  atomicAdd(&denLDS[l16], den0);
  atomicAdd(&denLDS[16 + l16], den1);
  #pragma unroll
  for (int cf = 0; cf < 8; ++cf) {
    #pragma unroll
    for (int r = 0; r < 4; ++r) {
      const int irow = (lk << 2) + r;  // C/D: row=(lane>>4)*4+reg, col=lane&15
      atomicAdd(&numLDS[irow * DD + cf * 16 + l16], acc0[cf][r]);
      atomicAdd(&numLDS[(16 + irow) * DD + cf * 16 + l16], acc1[cf][r]);
    }
  }
  __syncthreads();

  // epilogue: divide by denom, ELU, write f32 out (coalesced)
  const int row = t >> 4;
  const int c0 = (t & 15) << 3;
  const float rd = 1.f / denLDS[row];
  f32x4 o0, o1;
  #pragma unroll
  for (int q = 0; q < 4; ++q) {
    float v = numLDS[row * DD + c0 + q] * rd;
    o0[q] = v > 0.f ? v : (__expf(v) - 1.f);
    v = numLDS[row * DD + c0 + 4 + q] * rd;
    o1[q] = v > 0.f ? v : (__expf(v) - 1.f);
  }
  float* op = out + (size_t)(rowbase + row) * DD + c0;
  *(f32x4*)op = o0;
  *(f32x4*)(op + 4) = o1;
}

extern "C" void kernel_launch(void* const* d_in, const int* in_sizes, int n_in,
                              void* d_out, int out_size, void* d_ws, size_t ws_size,
                              hipStream_t stream) {
  const float* X = (const float*)d_in[0];
  const int* A = (const int*)d_in[1];
  const float* W = (const float*)d_in[2];
  const float* a_src = (const float*)d_in[3];
  const float* a_dst = (const float*)d_in[4];
  float* out = (float*)d_out;

  char* w = (char*)d_ws;
  unsigned* bitsv = (unsigned*)(w + 0);       // 8 MB
  bf16_t* HbT = (bf16_t*)(w + 8388608);       // 2 MB
  float* es = (float*)(w + 10485760);         // 32 KB
  float* ed = (float*)(w + 10518528);         // 32 KB  (total ~10.1 MB)

  hipLaunchKernelGGL(kA_pack, dim3(NN * NN / 32 / 256), dim3(256), 0, stream, A, bitsv);
  hipLaunchKernelGGL(k1_fused, dim3(256), dim3(256), 0, stream, X, W, a_src, a_dst, es,
                     ed, HbT);
  hipLaunchKernelGGL(k2_gat, dim3(256), dim3(512), 0, stream, bitsv, es, ed, HbT, out);
}

// Round 7
// 219.141 us; speedup vs baseline: 1.1556x; 1.1556x over previous
//
#include <hip/hip_runtime.h>
#include <hip/hip_bf16.h>

// GATConv, N=8192, F_in=F_out=128, dense 0/1 adjacency (int32).
// Rank-1 logits: e_ij = LeakyReLU(es_i + ed_j).  Separable exp:
//   exp(LeakyReLU(es+ed)) = (es+ed>0) ? exp(es)exp(ed) : exp(.2es)exp(.2ed)
//   and (es+ed>0) <=> exp(ed) > exp(-es)   (monotone)
// so the 67M-edge inner loop has NO transcendentals: F1/F2 precomputed per j,
// E1/E2/T per-lane constants. Partial sums additive (no softmax max-shift
// needed; |logit| small).
//
// R5 vs R4 (resubmitted; two consecutive container failures, never executed):
// kA drops nontemporal (L1 line reuse across the 8 sub-loads); k2 exp-free
// inner loop + 1024-thr blocks (4 waves/SIMD) with waves split 2x rows /
// 8x cols (32 VGPR acc, half the atomic contention).

typedef __bf16 bf16_t;
typedef bf16_t bf16x8 __attribute__((ext_vector_type(8)));
typedef float  f32x4  __attribute__((ext_vector_type(4)));
typedef int    i32x4  __attribute__((ext_vector_type(4)));

#define NN 8192
#define DD 128
#define NW 256  // mask words per row (8192/32)

// ---- kA: pack adjacency to bitmask, self-loop diagonal OR'd in ----
// Thread w reads its 128-B chunk (8x16B, plain loads -> L1 reuse), writes 4 B.
__global__ __launch_bounds__(256) void kA_pack(const int* __restrict__ A,
                                               unsigned* __restrict__ bits) {
  const int w = blockIdx.x * 256 + threadIdx.x;  // word id, 0..2M-1
  const i32x4* p = (const i32x4*)(A + (size_t)w * 32);
  i32x4 v[8];
  #pragma unroll
  for (int q = 0; q < 8; ++q) v[q] = p[q];
  unsigned m = 0;
  #pragma unroll
  for (int q = 0; q < 8; ++q) {
    #pragma unroll
    for (int e = 0; e < 4; ++e) m |= ((unsigned)v[q][e]) << (q * 4 + e);  // A is 0/1
  }
  const int row = w >> 8;         // w / NW
  const int c0 = (w & 255) << 5;  // first col of this word
  if (row >= c0 && row < c0 + 32) m |= 1u << (row - c0);  // self-loop
  bits[w] = m;
}

// ---- K1: fused wv = W@a_{src,dst}; es, Fv (exp tables); HbT = bf16(X@W)^T ----
__global__ __launch_bounds__(512) void k1_fused(const float* __restrict__ X,
                                                const float* __restrict__ W,
                                                const float* __restrict__ a_src,
                                                const float* __restrict__ a_dst,
                                                float* __restrict__ es,
                                                float* __restrict__ Fv,
                                                bf16_t* __restrict__ HbT) {
  __shared__ float Wl[DD * DD];    // 64 KB; [0..256) wsv/wdv, [256..320) es/ed scratch
  __shared__ bf16_t Tl[DD][40];    // transposed H tile [c][r]
  const int t = threadIdx.x;
  const int rb = blockIdx.x << 5;  // 32 rows per block

  // Phase 1: wsv (t<128) / wdv (128<=t<256)
  if (t < 256) {
    const int k = t & 127;
    const float* av = (t < 128) ? a_src : a_dst;
    const f32x4* wrow = (const f32x4*)(W + k * DD);
    float s = 0.f;
    #pragma unroll
    for (int c4 = 0; c4 < 32; ++c4) {
      const f32x4 wv = wrow[c4];
      const f32x4 avv = *(const f32x4*)(av + c4 * 4);
      s += wv[0] * avv[0] + wv[1] * avv[1] + wv[2] * avv[2] + wv[3] * avv[3];
    }
    Wl[t] = s;
  }
  if (t < 64) Wl[256 + t] = 0.f;
  __syncthreads();

  // Phase 2: es/ed partials; thread: r = t>>4 (32 rows), part = t&15 (8 cols each)
  {
    const int r = t >> 4, part = t & 15;
    const f32x4* xrow = (const f32x4*)(X + (size_t)(rb + r) * DD + part * 8);
    float s = 0.f, d = 0.f;
    #pragma unroll
    for (int q = 0; q < 2; ++q) {
      const f32x4 xv = xrow[q];
      const f32x4 sv = *(const f32x4*)(Wl + part * 8 + q * 4);
      const f32x4 dv = *(const f32x4*)(Wl + 128 + part * 8 + q * 4);
      s += xv[0] * sv[0] + xv[1] * sv[1] + xv[2] * sv[2] + xv[3] * sv[3];
      d += xv[0] * dv[0] + xv[1] * dv[1] + xv[2] * dv[2] + xv[3] * dv[3];
    }
    atomicAdd(&Wl[256 + r], s);
    atomicAdd(&Wl[288 + r], d);
  }
  __syncthreads();
  if (t < 32) {
    es[rb + t] = Wl[256 + t];
  } else if (t < 64) {
    const int j = rb + t - 32;
    const float d = Wl[288 + t - 32];
    Fv[2 * j] = __expf(d);             // F1 = exp(ed_j)
    Fv[2 * j + 1] = __expf(0.2f * d);  // F2 = exp(0.2*ed_j)
  }
  __syncthreads();

  // Phase 3: stage full W in LDS
  for (int idx = t; idx < DD * DD; idx += 512) Wl[idx] = W[idx];
  __syncthreads();

  // Phase 4: H tile -> LDS transposed. c = t&127, r0 = t>>7 (0..3)
  const int c = t & 127;
  const int r0 = t >> 7;
  for (int rr = 0; rr < 8; ++rr) {
    const int r = (rr << 2) + r0;
    const f32x4* xrow = (const f32x4*)(X + (size_t)(rb + r) * DD);
    float acc = 0.f;
    #pragma unroll
    for (int k4 = 0; k4 < 32; ++k4) {
      const f32x4 xv = xrow[k4];
      acc += xv[0] * Wl[(k4 * 4 + 0) * DD + c] + xv[1] * Wl[(k4 * 4 + 1) * DD + c] +
             xv[2] * Wl[(k4 * 4 + 2) * DD + c] + xv[3] * Wl[(k4 * 4 + 3) * DD + c];
    }
    Tl[c][r] = (bf16_t)acc;
  }
  __syncthreads();

  // write-out: c2 = t>>2 (column), q = t&3 (8-row chunk)
  {
    const int c2 = t >> 2, q = t & 3;
    const bf16x8 u = *(const bf16x8*)&Tl[c2][q * 8];
    *(bf16x8*)(HbT + (size_t)c2 * NN + rb + q * 8) = u;
  }
}

// ---- K2: main. 256 WGs x 1024 thr (16 waves = 4/SIMD). WG owns 32 rows. ----
// wave = (wr, wjj): wr in {0,1} -> rows wr*16..+16; wjj in 0..7 -> j range
// [wjj*1024, +1024), 32 steps of 32 j. Inner loop: bit-select of precomputed
// exp products (no transcendentals), 8 MFMA per step.
__global__ __launch_bounds__(1024, 4) void k2_gat(const unsigned* __restrict__ bits,
                                                  const float* __restrict__ es,
                                                  const float* __restrict__ Fv,
                                                  const bf16_t* __restrict__ HbT,
                                                  float* __restrict__ out) {
  __shared__ float numLDS[32 * DD];  // 16 KB
  __shared__ float denLDS[32];
  const int t = threadIdx.x;
  for (int idx = t; idx < 32 * DD; idx += 1024) numLDS[idx] = 0.f;
  if (t < 32) denLDS[t] = 0.f;
  __syncthreads();

  const int wave = t >> 6;
  const int lane = t & 63;
  const int l16 = lane & 15;
  const int lk = lane >> 4;      // 0..3
  const int wr = wave >> 3;      // row half
  const int wjj = wave & 7;      // j range
  const int rowbase = blockIdx.x << 5;
  const int i0 = rowbase + (wr << 4) + l16;
  const float esv = es[i0];
  const float E1 = __expf(esv);
  const float E2 = __expf(0.2f * esv);
  const float Tv = __expf(-esv);  // (es+ed>0) <=> F1 > Tv
  const unsigned* M0 = bits + (size_t)i0 * NW;
  const int wj = wjj << 10;

  f32x4 acc[8];
  #pragma unroll
  for (int cf = 0; cf < 8; ++cf) acc[cf] = f32x4{0.f, 0.f, 0.f, 0.f};
  float den = 0.f;

  i32x4 m0 = *(const i32x4*)(M0 + (wjj << 5));

  #pragma unroll 1
  for (int g = 0; g < 8; ++g) {
    i32x4 n0 = m0;
    if (g < 7) n0 = *(const i32x4*)(M0 + (wjj << 5) + ((g + 1) << 2));
    #pragma unroll
    for (int ds = 0; ds < 4; ++ds) {
      const int jj = wj + (((g << 2) + ds) << 5) + (lk << 3);
      const unsigned w0 = ((unsigned)m0[ds]) >> (lk << 3);
      const f32x4* fp = (const f32x4*)(Fv + (jj << 1));
      const f32x4 fA = fp[0], fB = fp[1], fC = fp[2], fD = fp[3];
      bf16x8 pa;
      float ps = 0.f;
      float p;
      p = ((w0 >> 0) & 1u) ? ((fA[0] > Tv) ? E1 * fA[0] : E2 * fA[1]) : 0.f; ps += p; pa[0] = (bf16_t)p;
      p = ((w0 >> 1) & 1u) ? ((fA[2] > Tv) ? E1 * fA[2] : E2 * fA[3]) : 0.f; ps += p; pa[1] = (bf16_t)p;
      p = ((w0 >> 2) & 1u) ? ((fB[0] > Tv) ? E1 * fB[0] : E2 * fB[1]) : 0.f; ps += p; pa[2] = (bf16_t)p;
      p = ((w0 >> 3) & 1u) ? ((fB[2] > Tv) ? E1 * fB[2] : E2 * fB[3]) : 0.f; ps += p; pa[3] = (bf16_t)p;
      p = ((w0 >> 4) & 1u) ? ((fC[0] > Tv) ? E1 * fC[0] : E2 * fC[1]) : 0.f; ps += p; pa[4] = (bf16_t)p;
      p = ((w0 >> 5) & 1u) ? ((fC[2] > Tv) ? E1 * fC[2] : E2 * fC[3]) : 0.f; ps += p; pa[5] = (bf16_t)p;
      p = ((w0 >> 6) & 1u) ? ((fD[0] > Tv) ? E1 * fD[0] : E2 * fD[1]) : 0.f; ps += p; pa[6] = (bf16_t)p;
      p = ((w0 >> 7) & 1u) ? ((fD[2] > Tv) ? E1 * fD[2] : E2 * fD[3]) : 0.f; ps += p; pa[7] = (bf16_t)p;
      den += ps;
      const bf16_t* vbase = HbT + jj;
      #pragma unroll
      for (int cf = 0; cf < 8; ++cf) {
        const bf16x8 vb = *(const bf16x8*)(vbase + (size_t)(cf * 16 + l16) * NN);
        acc[cf] = __builtin_amdgcn_mfma_f32_16x16x32_bf16(pa, vb, acc[cf], 0, 0, 0);
      }
    }
    m0 = n0;
  }

  // cross-wave reduction (order-independent additive sums)
  atomicAdd(&denLDS[(wr << 4) + l16], den);
  #pragma unroll
  for (int cf = 0; cf < 8; ++cf) {
    #pragma unroll
    for (int r = 0; r < 4; ++r) {
      const int irow = (wr << 4) + (lk << 2) + r;  // C/D: row=(lane>>4)*4+reg, col=lane&15
      atomicAdd(&numLDS[irow * DD + cf * 16 + l16], acc[cf][r]);
    }
  }
  __syncthreads();

  // epilogue: divide by denom, ELU, write f32 out (coalesced)
  const int row = t >> 5;        // 0..31
  const int c0 = (t & 31) << 2;  // 0..124
  const float rd = 1.f / denLDS[row];
  f32x4 o;
  #pragma unroll
  for (int q = 0; q < 4; ++q) {
    float v = numLDS[row * DD + c0 + q] * rd;
    o[q] = v > 0.f ? v : (__expf(v) - 1.f);
  }
  *(f32x4*)(out + (size_t)(rowbase + row) * DD + c0) = o;
}

extern "C" void kernel_launch(void* const* d_in, const int* in_sizes, int n_in,
                              void* d_out, int out_size, void* d_ws, size_t ws_size,
                              hipStream_t stream) {
  const float* X = (const float*)d_in[0];
  const int* A = (const int*)d_in[1];
  const float* W = (const float*)d_in[2];
  const float* a_src = (const float*)d_in[3];
  const float* a_dst = (const float*)d_in[4];
  float* out = (float*)d_out;

  char* w = (char*)d_ws;
  unsigned* bitsv = (unsigned*)(w + 0);     // 8 MB
  bf16_t* HbT = (bf16_t*)(w + 8388608);     // 2 MB
  float* es = (float*)(w + 10485760);       // 32 KB
  float* Fv = (float*)(w + 10518528);       // 64 KB (F1,F2 interleaved)

  hipLaunchKernelGGL(kA_pack, dim3(NN * NN / 32 / 256), dim3(256), 0, stream, A, bitsv);
  hipLaunchKernelGGL(k1_fused, dim3(256), dim3(512), 0, stream, X, W, a_src, a_dst, es,
                     Fv, HbT);
  hipLaunchKernelGGL(k2_gat, dim3(256), dim3(1024), 0, stream, bitsv, es, Fv, HbT, out);
}

// Round 9
// 179.681 us; speedup vs baseline: 1.4093x; 1.2196x over previous
//
#include <hip/hip_runtime.h>
#include <hip/hip_bf16.h>

// GATConv, N=8192, F_in=F_out=128, dense 0/1 adjacency (int32).
// Rank-1 logits: e_ij = LeakyReLU(es_i + ed_j).  Separable exp:
//   exp(LeakyReLU(es+ed)) = (es+ed>0) ? exp(es)exp(ed) : exp(.2es)exp(.2ed)
//   and (es+ed>0) <=> exp(ed) > exp(-es)   (monotone, exact)
// R9 = R8 + replay-safety fix: accumulators (num=d_out, denP) are zeroed by a
// KERNEL, not hipMemsetAsync (R8 post-timing divergence proved the memsets
// were not replayed in the captured graph -> denP accumulated across replays).

typedef __bf16 bf16_t;
typedef bf16_t bf16x8 __attribute__((ext_vector_type(8)));
typedef float  f32x4  __attribute__((ext_vector_type(4)));
typedef int    i32x4  __attribute__((ext_vector_type(4)));

#define NN 8192
#define DD 128

// ---- k0: zero the accumulators (graph-captured, runs every replay) ----
__global__ __launch_bounds__(256) void k0_zero(float* __restrict__ out,
                                               float* __restrict__ denP) {
  const int idx = blockIdx.x * 256 + threadIdx.x;
  ((f32x4*)out)[idx] = f32x4{0.f, 0.f, 0.f, 0.f};     // 262144 x 16B = 4 MB
  if (idx < NN / 4) ((f32x4*)denP)[idx] = f32x4{0.f, 0.f, 0.f, 0.f};
}

// ---- kA: pack adjacency to bitmask, self-loop diagonal OR'd in ----
__global__ __launch_bounds__(256) void kA_pack(const int* __restrict__ A,
                                               unsigned* __restrict__ bits) {
  const int w = blockIdx.x * 256 + threadIdx.x;  // word id, 0..2M-1
  const i32x4* p = (const i32x4*)(A + (size_t)w * 32);
  i32x4 v[8];
  #pragma unroll
  for (int q = 0; q < 8; ++q) v[q] = p[q];
  unsigned m = 0;
  #pragma unroll
  for (int q = 0; q < 8; ++q) {
    #pragma unroll
    for (int e = 0; e < 4; ++e) m |= ((unsigned)v[q][e]) << (q * 4 + e);  // A is 0/1
  }
  const int row = w >> 8;         // w / 256
  const int c0 = (w & 255) << 5;  // first col of this word
  if (row >= c0 && row < c0 + 32) m |= 1u << (row - c0);  // self-loop
  bits[w] = m;
}

// ---- K1: fused wv = W@a_{src,dst}; es, Fv (exp tables); HbT = bf16(X@W)^T ----
__global__ __launch_bounds__(512) void k1_fused(const float* __restrict__ X,
                                                const float* __restrict__ W,
                                                const float* __restrict__ a_src,
                                                const float* __restrict__ a_dst,
                                                float* __restrict__ es,
                                                float* __restrict__ Fv,
                                                bf16_t* __restrict__ HbT) {
  __shared__ float Wl[DD * DD];
  __shared__ bf16_t Tl[DD][40];
  const int t = threadIdx.x;
  const int rb = blockIdx.x << 5;

  if (t < 256) {
    const int k = t & 127;
    const float* av = (t < 128) ? a_src : a_dst;
    const f32x4* wrow = (const f32x4*)(W + k * DD);
    float s = 0.f;
    #pragma unroll
    for (int c4 = 0; c4 < 32; ++c4) {
      const f32x4 wv = wrow[c4];
      const f32x4 avv = *(const f32x4*)(av + c4 * 4);
      s += wv[0] * avv[0] + wv[1] * avv[1] + wv[2] * avv[2] + wv[3] * avv[3];
    }
    Wl[t] = s;
  }
  if (t < 64) Wl[256 + t] = 0.f;
  __syncthreads();

  {
    const int r = t >> 4, part = t & 15;
    const f32x4* xrow = (const f32x4*)(X + (size_t)(rb + r) * DD + part * 8);
    float s = 0.f, d = 0.f;
    #pragma unroll
    for (int q = 0; q < 2; ++q) {
      const f32x4 xv = xrow[q];
      const f32x4 sv = *(const f32x4*)(Wl + part * 8 + q * 4);
      const f32x4 dv = *(const f32x4*)(Wl + 128 + part * 8 + q * 4);
      s += xv[0] * sv[0] + xv[1] * sv[1] + xv[2] * sv[2] + xv[3] * sv[3];
      d += xv[0] * dv[0] + xv[1] * dv[1] + xv[2] * dv[2] + xv[3] * dv[3];
    }
    atomicAdd(&Wl[256 + r], s);
    atomicAdd(&Wl[288 + r], d);
  }
  __syncthreads();
  if (t < 32) {
    es[rb + t] = Wl[256 + t];
  } else if (t < 64) {
    const int j = rb + t - 32;
    const float d = Wl[288 + t - 32];
    Fv[2 * j] = __expf(d);
    Fv[2 * j + 1] = __expf(0.2f * d);
  }
  __syncthreads();

  for (int idx = t; idx < DD * DD; idx += 512) Wl[idx] = W[idx];
  __syncthreads();

  const int c = t & 127;
  const int r0 = t >> 7;
  for (int rr = 0; rr < 8; ++rr) {
    const int r = (rr << 2) + r0;
    const f32x4* xrow = (const f32x4*)(X + (size_t)(rb + r) * DD);
    float acc = 0.f;
    #pragma unroll
    for (int k4 = 0; k4 < 32; ++k4) {
      const f32x4 xv = xrow[k4];
      acc += xv[0] * Wl[(k4 * 4 + 0) * DD + c] + xv[1] * Wl[(k4 * 4 + 1) * DD + c] +
             xv[2] * Wl[(k4 * 4 + 2) * DD + c] + xv[3] * Wl[(k4 * 4 + 3) * DD + c];
    }
    Tl[c][r] = (bf16_t)acc;
  }
  __syncthreads();

  {
    const int c2 = t >> 2, q = t & 3;
    const bf16x8 u = *(const bf16x8*)&Tl[c2][q * 8];
    *(bf16x8*)(HbT + (size_t)c2 * NN + rb + q * 8) = u;
  }
}

// ---- K2: LDS-staged masked GEMM partial. 512 blocks x 512 thr (8 waves). ----
// Block: rows rowbase..+64, j in [jqb, jqb+2048), 16 K-iters of 128 j.
// Waves: wr = wave>>1 (16-row group), wc = wave&1 (64-col group, 4 col-frags).
// LDS tiles XOR-swizzled: phys_byte = row*256 + (jbyte ^ ((row&7)<<4)).
__global__ __launch_bounds__(512, 4) void k2_gat(const unsigned char* __restrict__ bits8,
                                                 const float* __restrict__ es,
                                                 const float* __restrict__ Fv,
                                                 const bf16_t* __restrict__ HbT,
                                                 float* __restrict__ num,
                                                 float* __restrict__ denP) {
  __shared__ __align__(16) unsigned char Vl[128 * 256];  // 32 KB [c][j]
  __shared__ __align__(16) unsigned char Pl[64 * 256];   // 16 KB [r][j]
  __shared__ float denL[64];
  const int t = threadIdx.x;
  const int rowbase = (blockIdx.x >> 2) << 6;
  const int jqb = (blockIdx.x & 3) << 11;

  // P-stage ids: thread -> (row pr, 16-j chunk pjb)
  const int pr = t >> 3;
  const int pjb = t & 7;
  const float esv = es[rowbase + pr];
  const float E1 = __expf(esv);
  const float E2 = __expf(0.2f * esv);
  const float Tv = __expf(-esv);  // (es+ed>0) <=> exp(ed) > Tv
  // V-stage ids: thread -> (col vc, 32-j chunk vjq)
  const int vc = t >> 2;
  const int vjq = t & 3;
  // wave/frag ids
  const int wave = t >> 6, lane = t & 63, l16 = lane & 15, lk = lane >> 4;
  const int wr = wave >> 1, wc = wave & 1;
  const int r_l = (wr << 4) + l16;
  const int abase = r_l * 256, aswz = (r_l & 7) << 4;
  int bbase[4], bswz[4];
  #pragma unroll
  for (int cf = 0; cf < 4; ++cf) {
    const int c = (wc << 6) + (cf << 4) + l16;
    bbase[cf] = c * 256;
    bswz[cf] = (c & 7) << 4;
  }

  if (t < 64) denL[t] = 0.f;
  f32x4 acc[4];
  #pragma unroll
  for (int cf = 0; cf < 4; ++cf) acc[cf] = f32x4{0.f, 0.f, 0.f, 0.f};
  float dsum = 0.f;

  const bf16_t* vsrc = HbT + (size_t)vc * NN + jqb + vjq * 32;
  const unsigned char* msrc = bits8 + (size_t)(rowbase + pr) * 1024 + (jqb >> 3) + pjb * 2;
  const float* fsrc = Fv + (jqb << 1) + (pjb << 5);

  #pragma unroll 1
  for (int it = 0; it < 16; ++it) {
    // (1) issue V global loads (64 B contiguous per thread; latency hides under P)
    const i32x4* vp = (const i32x4*)(vsrc + (it << 7));
    const i32x4 v0 = vp[0], v1 = vp[1], v2 = vp[2], v3 = vp[3];
    // (2) compute P for (pr, 16 j) — exp-free select chain
    const unsigned mb = *(const unsigned short*)(msrc + (it << 4));
    const f32x4* fp = (const f32x4*)(fsrc + (it << 8));
    bf16x8 p0, p1;
    float ps = 0.f;
    #pragma unroll
    for (int q = 0; q < 16; ++q) {
      const f32x4 fq = fp[q >> 1];
      const float f1 = (q & 1) ? fq[2] : fq[0];
      const float f2 = (q & 1) ? fq[3] : fq[1];
      const float p = ((mb >> q) & 1u) ? ((f1 > Tv) ? E1 * f1 : E2 * f2) : 0.f;
      ps += p;
      if (q < 8) p0[q] = (bf16_t)p;
      else p1[q - 8] = (bf16_t)p;
    }
    dsum += ps;
    __syncthreads();  // previous iter's compute done reading Vl/Pl
    // (3) LDS writes, swizzled
    *(bf16x8*)(Pl + pr * 256 + (((pjb << 5) + 0) ^ ((pr & 7) << 4))) = p0;
    *(bf16x8*)(Pl + pr * 256 + (((pjb << 5) + 16) ^ ((pr & 7) << 4))) = p1;
    *(i32x4*)(Vl + vc * 256 + (((vjq << 6) + 0) ^ ((vc & 7) << 4))) = v0;
    *(i32x4*)(Vl + vc * 256 + (((vjq << 6) + 16) ^ ((vc & 7) << 4))) = v1;
    *(i32x4*)(Vl + vc * 256 + (((vjq << 6) + 32) ^ ((vc & 7) << 4))) = v2;
    *(i32x4*)(Vl + vc * 256 + (((vjq << 6) + 48) ^ ((vc & 7) << 4))) = v3;
    __syncthreads();  // tiles visible
    // (4) 4 k-steps of 32 j: ds_read_b128 + MFMA only
    #pragma unroll
    for (int ks = 0; ks < 4; ++ks) {
      const int kb2 = (ks << 6) + (lk << 4);  // byte offset of j = ks*32 + lk*8
      const bf16x8 pa = *(const bf16x8*)(Pl + abase + (kb2 ^ aswz));
      #pragma unroll
      for (int cf = 0; cf < 4; ++cf) {
        const bf16x8 vb = *(const bf16x8*)(Vl + bbase[cf] + (kb2 ^ bswz[cf]));
        acc[cf] = __builtin_amdgcn_mfma_f32_16x16x32_bf16(pa, vb, acc[cf], 0, 0, 0);
      }
    }
  }

  // denominator partials: per-thread sum -> LDS -> one global atomic per row
  atomicAdd(&denL[pr], dsum);
  __syncthreads();
  if (t < 64) atomicAdd(&denP[rowbase + t], denL[t]);

  // numerator partials -> global f32 atomics (4 j-quarter blocks per row-tile)
  #pragma unroll
  for (int cf = 0; cf < 4; ++cf) {
    const int col = (wc << 6) + (cf << 4) + l16;
    #pragma unroll
    for (int r = 0; r < 4; ++r) {
      const int row = rowbase + (wr << 4) + (lk << 2) + r;  // C/D: row=(lane>>4)*4+reg
      atomicAdd(&num[(size_t)row * DD + col], acc[cf][r]);
    }
  }
}

// ---- K3: out = elu(num / den), in place on d_out ----
__global__ __launch_bounds__(256) void k3_elu(float* __restrict__ out,
                                              const float* __restrict__ denP) {
  const int base = (blockIdx.x * 256 + threadIdx.x) * 8;
  const float rd = 1.f / denP[base >> 7];
  f32x4 a = *(f32x4*)(out + base);
  f32x4 b = *(f32x4*)(out + base + 4);
  #pragma unroll
  for (int q = 0; q < 4; ++q) {
    float v = a[q] * rd;
    a[q] = v > 0.f ? v : (__expf(v) - 1.f);
    v = b[q] * rd;
    b[q] = v > 0.f ? v : (__expf(v) - 1.f);
  }
  *(f32x4*)(out + base) = a;
  *(f32x4*)(out + base + 4) = b;
}

extern "C" void kernel_launch(void* const* d_in, const int* in_sizes, int n_in,
                              void* d_out, int out_size, void* d_ws, size_t ws_size,
                              hipStream_t stream) {
  const float* X = (const float*)d_in[0];
  const int* A = (const int*)d_in[1];
  const float* W = (const float*)d_in[2];
  const float* a_src = (const float*)d_in[3];
  const float* a_dst = (const float*)d_in[4];
  float* out = (float*)d_out;

  char* w = (char*)d_ws;
  unsigned* bitsv = (unsigned*)(w + 0);     // 8 MB
  bf16_t* HbT = (bf16_t*)(w + 8388608);     // 2 MB
  float* es = (float*)(w + 10485760);       // 32 KB
  float* Fv = (float*)(w + 10518528);       // 64 KB (F1,F2 interleaved)
  float* denP = (float*)(w + 10584064);     // 32 KB

  hipLaunchKernelGGL(k0_zero, dim3(NN * DD / 4 / 256), dim3(256), 0, stream, out, denP);
  hipLaunchKernelGGL(kA_pack, dim3(NN * NN / 32 / 256), dim3(256), 0, stream, A, bitsv);
  hipLaunchKernelGGL(k1_fused, dim3(256), dim3(512), 0, stream, X, W, a_src, a_dst, es,
                     Fv, HbT);
  hipLaunchKernelGGL(k2_gat, dim3(512), dim3(512), 0, stream,
                     (const unsigned char*)bitsv, es, Fv, HbT, out, denP);
  hipLaunchKernelGGL(k3_elu, dim3(512), dim3(256), 0, stream, out, denP);
}

// Round 10
// 125.025 us; speedup vs baseline: 2.0255x; 1.4372x over previous
//
#include <hip/hip_runtime.h>
#include <hip/hip_bf16.h>

// GATConv, N=8192, F_in=F_out=128, dense 0/1 adjacency (int32).
// Rank-1 logits: e_ij = LeakyReLU(es_i + ed_j), es = X@(W@a_src), ed = X@(W@a_dst).
// exp safe in f32 (|logit| small) -> plain additive softmax partials, no max-shift.
//
// R10: single fused A-paced kernel. k2 streams raw A (256 MB, the mandatory
// traffic) with register double-buffer + counted vmcnt(8) + raw s_barrier
// (T3/T4-lite); P computed in-register in the MFMA A-frag layout (computing
// thread == consuming lane); V staged via global_load_lds with pre-swizzled
// per-lane global source (linear LDS dest, XOR on read); jsub partials merged
// in LDS; 4 j-quarter num partials plain-stored (no atomics); k3 combines.

typedef __bf16 bf16_t;
typedef bf16_t bf16x8 __attribute__((ext_vector_type(8)));
typedef float  f32x4  __attribute__((ext_vector_type(4)));
typedef int    i32x4  __attribute__((ext_vector_type(4)));

#define NN 8192
#define DD 128
#define JSPLIT 4
#define BK 64
#define ITERS ((NN / JSPLIT) / BK)  // 32

#define GLOAD_LDS16(src, dst)                                                  \
  __builtin_amdgcn_global_load_lds(                                            \
      (const __attribute__((address_space(1))) unsigned int*)(src),            \
      (__attribute__((address_space(3))) unsigned int*)(dst), 16, 0, 0)

// ---- K1: fused wv = W@a_{src,dst}; es/ed; HbT = bf16(X@W)^T ----
__global__ __launch_bounds__(512) void k1_fused(const float* __restrict__ X,
                                                const float* __restrict__ W,
                                                const float* __restrict__ a_src,
                                                const float* __restrict__ a_dst,
                                                float* __restrict__ es,
                                                float* __restrict__ edv,
                                                bf16_t* __restrict__ HbT) {
  __shared__ float Wl[DD * DD];    // 64 KB; [0..256) wsv/wdv, [256..320) es/ed scratch
  __shared__ bf16_t Tl[DD][40];    // transposed H tile [c][r]
  const int t = threadIdx.x;
  const int rb = blockIdx.x << 5;  // 32 rows per block

  if (t < 256) {
    const int k = t & 127;
    const float* av = (t < 128) ? a_src : a_dst;
    const f32x4* wrow = (const f32x4*)(W + k * DD);
    float s = 0.f;
    #pragma unroll
    for (int c4 = 0; c4 < 32; ++c4) {
      const f32x4 wv = wrow[c4];
      const f32x4 avv = *(const f32x4*)(av + c4 * 4);
      s += wv[0] * avv[0] + wv[1] * avv[1] + wv[2] * avv[2] + wv[3] * avv[3];
    }
    Wl[t] = s;
  }
  if (t < 64) Wl[256 + t] = 0.f;
  __syncthreads();

  {
    const int r = t >> 4, part = t & 15;
    const f32x4* xrow = (const f32x4*)(X + (size_t)(rb + r) * DD + part * 8);
    float s = 0.f, d = 0.f;
    #pragma unroll
    for (int q = 0; q < 2; ++q) {
      const f32x4 xv = xrow[q];
      const f32x4 sv = *(const f32x4*)(Wl + part * 8 + q * 4);
      const f32x4 dv = *(const f32x4*)(Wl + 128 + part * 8 + q * 4);
      s += xv[0] * sv[0] + xv[1] * sv[1] + xv[2] * sv[2] + xv[3] * sv[3];
      d += xv[0] * dv[0] + xv[1] * dv[1] + xv[2] * dv[2] + xv[3] * dv[3];
    }
    atomicAdd(&Wl[256 + r], s);
    atomicAdd(&Wl[288 + r], d);
  }
  __syncthreads();
  if (t < 32) {
    es[rb + t] = Wl[256 + t];
  } else if (t < 64) {
    edv[rb + t - 32] = Wl[288 + t - 32];
  }
  __syncthreads();

  for (int idx = t; idx < DD * DD; idx += 512) Wl[idx] = W[idx];
  __syncthreads();

  const int c = t & 127;
  const int r0 = t >> 7;
  for (int rr = 0; rr < 8; ++rr) {
    const int r = (rr << 2) + r0;
    const f32x4* xrow = (const f32x4*)(X + (size_t)(rb + r) * DD);
    float acc = 0.f;
    #pragma unroll
    for (int k4 = 0; k4 < 32; ++k4) {
      const f32x4 xv = xrow[k4];
      acc += xv[0] * Wl[(k4 * 4 + 0) * DD + c] + xv[1] * Wl[(k4 * 4 + 1) * DD + c] +
             xv[2] * Wl[(k4 * 4 + 2) * DD + c] + xv[3] * Wl[(k4 * 4 + 3) * DD + c];
    }
    Tl[c][r] = (bf16_t)acc;
  }
  __syncthreads();

  {
    const int c2 = t >> 2, q = t & 3;
    const bf16x8 u = *(const bf16x8*)&Tl[c2][q * 8];
    *(bf16x8*)(HbT + (size_t)c2 * NN + rb + q * 8) = u;
  }
}

// ---- K2: fused A-stream masked GEMM. 512 blocks (2/CU) x 512 thr (8 waves). ----
// Block = 64 rows x j-quarter (2048). Waves (wr, wc, js): rows wr*32+{0..31},
// cols wc*64+{0..63}, j-half js*32 within each BK=64 tile. 32 K-iters.
// Per iter/thread: 4 A dwordx4 + 2 ed dwordx4 (reg dbuf, 1 ahead) + 2
// global_load_lds (V, swizzled src); P in-reg (16 exp); 4 ds_read_b128; 8 MFMA.
__global__ __launch_bounds__(512, 4) void k2_gat(const int* __restrict__ A,
                                                 const float* __restrict__ es,
                                                 const float* __restrict__ edv,
                                                 const bf16_t* __restrict__ HbT,
                                                 float* __restrict__ num,
                                                 float* __restrict__ denP) {
  __shared__ __align__(16) unsigned char Vl[2][16384];  // V dbuf, [col][64j], 128B rows
  __shared__ float denL[64];
  const int t = threadIdx.x;
  const int lane = t & 63, wave = t >> 6;
  const int l16 = lane & 15, lk = lane >> 4;  // lk 0..3
  const int wr = wave >> 2, wc = (wave >> 1) & 1, js = wave & 1;
  const int rb = (blockIdx.x >> 2) << 6;
  const int jq = blockIdx.x & 3;
  const int jq0 = jq << 11;

  if (t < 64) denL[t] = 0.f;

  const int r0 = rb + (wr << 5) + l16;
  const int r1 = r0 + 16;
  const float es0 = es[r0], es1 = es[r1];

  const int jth = (js << 5) + (lk << 3);  // thread's j offset within BK tile
  const int* pA0 = A + (size_t)r0 * NN + jq0 + jth;
  const int* pA1 = A + (size_t)r1 * NN + jq0 + jth;
  const float* ped = edv + jq0 + jth;
  int jcur = jq0 + jth;

  // global_load_lds sources (2 chunks of 8KB): chunk k -> col = k*64 + t>>3
  const int colk0 = t >> 3, colk1 = 64 + (t >> 3);
  const int inner = (t & 7) << 4;
  const unsigned char* HB = (const unsigned char*)HbT;
  const unsigned char* pV0 =
      HB + (size_t)colk0 * (NN * 2) + (size_t)jq0 * 2 + (inner ^ ((colk0 & 7) << 4));
  const unsigned char* pV1 =
      HB + (size_t)colk1 * (NN * 2) + (size_t)jq0 * 2 + (inner ^ ((colk1 & 7) << 4));
  const int ldso0 = wave << 10;             // wave-uniform LDS chunk bases
  const int ldso1 = 8192 + (wave << 10);

  // ds_read vb offsets (per cf), fixed per thread: col*128 + (kb ^ swz)
  int voff[4];
  #pragma unroll
  for (int cf = 0; cf < 4; ++cf) {
    const int col = (wc << 6) + (cf << 4) + l16;
    voff[cf] = col * 128 + (((js << 6) + (lk << 4)) ^ ((col & 7) << 4));
  }

  f32x4 acc0[4], acc1[4];
  #pragma unroll
  for (int cf = 0; cf < 4; ++cf) {
    acc0[cf] = f32x4{0.f, 0.f, 0.f, 0.f};
    acc1[cf] = f32x4{0.f, 0.f, 0.f, 0.f};
  }
  float ds0 = 0.f, ds1 = 0.f;

  // prologue: iter-0 A/ed into regs, glds(0) -> buf0
  i32x4 a0A = *(const i32x4*)pA0, a0B = *(const i32x4*)(pA0 + 4);
  i32x4 a1A = *(const i32x4*)pA1, a1B = *(const i32x4*)(pA1 + 4);
  f32x4 e0A = *(const f32x4*)ped, e0B = *(const f32x4*)(ped + 4);
  GLOAD_LDS16(pV0, &Vl[0][ldso0]);
  GLOAD_LDS16(pV1, &Vl[0][ldso1]);
  i32x4 n0A, n0B, n1A, n1B;
  f32x4 f0A, f0B;

  #pragma unroll 1
  for (int it = 0; it < ITERS; ++it) {
    const int buf = it & 1;
    // ---- (1) issue next tile: 4 A + 2 ed + 2 glds  (window = 8) ----
    if (it + 1 < ITERS) {
      n0A = *(const i32x4*)(pA0 + BK);
      n0B = *(const i32x4*)(pA0 + BK + 4);
      n1A = *(const i32x4*)(pA1 + BK);
      n1B = *(const i32x4*)(pA1 + BK + 4);
      f0A = *(const f32x4*)(ped + BK);
      f0B = *(const f32x4*)(ped + BK + 4);
      GLOAD_LDS16(pV0 + 128, &Vl[buf ^ 1][ldso0]);
      GLOAD_LDS16(pV1 + 128, &Vl[buf ^ 1][ldso1]);
    }
    __builtin_amdgcn_sched_barrier(0);
    // ---- (2) P(t) in-reg: exp(LeakyReLU(es+ed)) masked by A>0 or diagonal ----
    bf16x8 pa0, pa1;
    {
      float s0 = 0.f, s1 = 0.f;
      #pragma unroll
      for (int e = 0; e < 8; ++e) {
        const int av0 = (e < 4) ? a0A[e] : a0B[e - 4];
        const int av1 = (e < 4) ? a1A[e] : a1B[e - 4];
        const float edq = (e < 4) ? e0A[e] : e0B[e - 4];
        float x0 = es0 + edq;
        x0 = fmaxf(x0, 0.2f * x0);
        float x1 = es1 + edq;
        x1 = fmaxf(x1, 0.2f * x1);
        const int j = jcur + e;
        const float p0 = (av0 > 0 || j == r0) ? __expf(x0) : 0.f;
        const float p1 = (av1 > 0 || j == r1) ? __expf(x1) : 0.f;
        s0 += p0;
        s1 += p1;
        pa0[e] = (bf16_t)p0;
        pa1[e] = (bf16_t)p1;
      }
      ds0 += s0;
      ds1 += s1;
    }
    __builtin_amdgcn_sched_barrier(0);
    // ---- (3) drain tile-t glds (counted: keep the 8 next-tile loads in flight) ----
    if (it + 1 < ITERS) {
      asm volatile("s_waitcnt vmcnt(8)" ::: "memory");
    } else {
      asm volatile("s_waitcnt vmcnt(0)" ::: "memory");
    }
    __builtin_amdgcn_s_barrier();
    __builtin_amdgcn_sched_barrier(0);
    // ---- (4) MFMA on tile t ----
    {
      const unsigned char* vb_base = &Vl[buf][0];
      #pragma unroll
      for (int cf = 0; cf < 4; ++cf) {
        const bf16x8 vb = *(const bf16x8*)(vb_base + voff[cf]);
        acc0[cf] = __builtin_amdgcn_mfma_f32_16x16x32_bf16(pa0, vb, acc0[cf], 0, 0, 0);
        acc1[cf] = __builtin_amdgcn_mfma_f32_16x16x32_bf16(pa1, vb, acc1[cf], 0, 0, 0);
      }
    }
    __builtin_amdgcn_sched_barrier(0);
    __builtin_amdgcn_s_barrier();  // reads done before next iter's glds overwrite
    // rotate
    a0A = n0A; a0B = n0B; a1A = n1A; a1B = n1B;
    e0A = f0A; e0B = f0B;
    pA0 += BK; pA1 += BK; ped += BK;
    pV0 += 128; pV1 += 128;
    jcur += BK;
  }

  // ---- epilogue: den partials + jsub merge via LDS, plain stores ----
  if (wc == 0) {
    atomicAdd(&denL[(wr << 5) + l16], ds0);
    atomicAdd(&denL[(wr << 5) + 16 + l16], ds1);
  }
  __syncthreads();
  if (t < 64) denP[(size_t)jq * NN + rb + t] = denL[t];
  float* M = (float*)&Vl[0][0];  // 32 KB merge scratch: 4 regions x 2048 f32
  const int mreg = ((wr << 1) + wc) << 11;
  if (js == 1) {
    #pragma unroll
    for (int cf = 0; cf < 4; ++cf) {
      #pragma unroll
      for (int rg = 0; rg < 4; ++rg) {
        M[mreg + ((lk << 2) + rg) * 64 + (cf << 4) + l16] = acc0[cf][rg];
        M[mreg + (16 + (lk << 2) + rg) * 64 + (cf << 4) + l16] = acc1[cf][rg];
      }
    }
  }
  __syncthreads();
  if (js == 0) {
    float* nq = num + (size_t)jq * (NN * DD);
    #pragma unroll
    for (int cf = 0; cf < 4; ++cf) {
      const int col = (wc << 6) + (cf << 4) + l16;
      #pragma unroll
      for (int rg = 0; rg < 4; ++rg) {
        const int rl0 = (lk << 2) + rg;
        nq[(size_t)(rb + (wr << 5) + rl0) * DD + col] =
            acc0[cf][rg] + M[mreg + rl0 * 64 + (cf << 4) + l16];
        nq[(size_t)(rb + (wr << 5) + 16 + rl0) * DD + col] =
            acc1[cf][rg] + M[mreg + (16 + rl0) * 64 + (cf << 4) + l16];
      }
    }
  }
}

// ---- K3: out = elu( (sum_q num_q) / (sum_q den_q) ) ----
__global__ __launch_bounds__(256) void k3_fin(const float* __restrict__ num,
                                              const float* __restrict__ denP,
                                              float* __restrict__ out) {
  const int g = blockIdx.x * 256 + threadIdx.x;  // 131072 threads x 8 floats
  const size_t b = (size_t)g * 8;
  const int row = (int)(b >> 7);
  float den = 0.f;
  #pragma unroll
  for (int q = 0; q < JSPLIT; ++q) den += denP[(size_t)q * NN + row];
  const float rd = 1.f / den;
  f32x4 s0 = {0.f, 0.f, 0.f, 0.f}, s1 = {0.f, 0.f, 0.f, 0.f};
  #pragma unroll
  for (int q = 0; q < JSPLIT; ++q) {
    const float* nb = num + (size_t)q * (NN * DD);
    s0 += *(const f32x4*)(nb + b);
    s1 += *(const f32x4*)(nb + b + 4);
  }
  #pragma unroll
  for (int e = 0; e < 4; ++e) {
    float v = s0[e] * rd;
    s0[e] = v > 0.f ? v : (__expf(v) - 1.f);
    v = s1[e] * rd;
    s1[e] = v > 0.f ? v : (__expf(v) - 1.f);
  }
  *(f32x4*)(out + b) = s0;
  *(f32x4*)(out + b + 4) = s1;
}

extern "C" void kernel_launch(void* const* d_in, const int* in_sizes, int n_in,
                              void* d_out, int out_size, void* d_ws, size_t ws_size,
                              hipStream_t stream) {
  const float* X = (const float*)d_in[0];
  const int* A = (const int*)d_in[1];
  const float* W = (const float*)d_in[2];
  const float* a_src = (const float*)d_in[3];
  const float* a_dst = (const float*)d_in[4];
  float* out = (float*)d_out;

  char* w = (char*)d_ws;
  bf16_t* HbT = (bf16_t*)(w + 0);            // 2 MB
  float* es = (float*)(w + 2097152);         // 32 KB
  float* edv = (float*)(w + 2129920);        // 32 KB
  float* denP = (float*)(w + 2162688);       // 4 x 32 KB
  float* num = (float*)(w + 2293760);        // 4 x 4 MB  (total ~18.5 MB)

  hipLaunchKernelGGL(k1_fused, dim3(256), dim3(512), 0, stream, X, W, a_src, a_dst, es,
                     edv, HbT);
  hipLaunchKernelGGL(k2_gat, dim3(512), dim3(512), 0, stream, A, es, edv, HbT, num,
                     denP);
  hipLaunchKernelGGL(k3_fin, dim3(512), dim3(256), 0, stream, num, denP, out);
}